// Round 1
// baseline (2449.838 us; speedup 1.0000x reference)
//
#include <hip/hip_runtime.h>

#define NNODES 100000
#define NEDGES 1600000
#define IN_CH 128
#define HID 64
#define HEADS 4
#define OUT_CH 16
#define OUT_SIZE 4
#define NEG_SLOPE 0.2f

// ---------------- degree (int atomics, deterministic) ----------------
__global__ void k_deg_count(const int* __restrict__ dst, int* __restrict__ deg, int E) {
    int e = blockIdx.x * blockDim.x + threadIdx.x;
    if (e < E) {
        int d = dst[e];
        if ((unsigned)d < NNODES) atomicAdd(&deg[d], 1);
    }
}

__global__ void k_deg_to_f(const int* __restrict__ deg, float* __restrict__ degf, int n) {
    int i = blockIdx.x * blockDim.x + threadIdx.x;
    if (i < n) degf[i] = (float)deg[i];
}

// ---------------- fused linear + attention scores ----------------
// block = 64 threads, one node per block. h = x@W^T + b ; si/sj per head.
__global__ void k_linear(const float* __restrict__ x, int in_ch,
                         const float* __restrict__ W, const float* __restrict__ b,
                         const float* __restrict__ att,
                         float* __restrict__ h, float* __restrict__ si, float* __restrict__ sj,
                         int n) {
    int node = blockIdx.x;
    if (node >= n) return;
    int t = threadIdx.x;  // 0..63 = output channel
    __shared__ float xs[IN_CH];
    __shared__ float hs[HID];
    for (int k = t; k < in_ch; k += 64) xs[k] = x[(size_t)node * in_ch + k];
    __syncthreads();
    float acc = b[t];
    const float* wrow = W + (size_t)t * in_ch;
    #pragma unroll 8
    for (int k = 0; k < in_ch; ++k) acc = fmaf(xs[k], wrow[k], acc);
    h[(size_t)node * HID + t] = acc;
    hs[t] = acc;
    __syncthreads();
    if (t < 2 * HEADS) {
        int head = t >> 1, part = t & 1;  // part 0 -> si (att[:, :C]), 1 -> sj (att[:, C:])
        const float* arow = att + head * (2 * OUT_CH) + part * OUT_CH;
        const float* hrow = hs + head * OUT_CH;
        float v = 0.f;
        #pragma unroll
        for (int c = 0; c < OUT_CH; ++c) v = fmaf(hrow[c], arow[c], v);
        if (part == 0) si[node * HEADS + head] = v;
        else           sj[node * HEADS + head] = v;
    }
}

// ---------------- edge scatter ----------------
// 64 threads (one channel each) per edge; 4 edges per 256-thread block.
#define EPB 4
__global__ void k_edge(const int* __restrict__ src, const int* __restrict__ dst,
                       const float* __restrict__ h, const float* __restrict__ si,
                       const float* __restrict__ sj, const float* __restrict__ degf,
                       float* __restrict__ out, int E) {
    int e = blockIdx.x * EPB + (threadIdx.x >> 6);
    if (e >= E) return;
    int t = threadIdx.x & 63;
    int s = src[e], d = dst[e];
    if ((unsigned)s >= NNODES || (unsigned)d >= NNODES) return;
    int head = t >> 4;
    float a = si[d * HEADS + head] + sj[s * HEADS + head];
    a = (a > 0.f) ? a : a * NEG_SLOPE;
    a = a / degf[d];   // true division to match reference rounding
    float v = h[(size_t)s * HID + t] * a;
    atomicAdd(&out[(size_t)d * HID + t], v);
}

// ---------------- final fc: out = x @ fcW^T + fcb ----------------
__global__ void k_fc(const float* __restrict__ x, const float* __restrict__ fcW,
                     const float* __restrict__ fcb, float* __restrict__ out, int n) {
    int i = blockIdx.x * blockDim.x + threadIdx.x;
    if (i >= n * OUT_SIZE) return;
    int node = i >> 2, o = i & 3;
    const float* xr = x + (size_t)node * HID;
    const float* wr = fcW + o * HID;
    float acc = fcb[o];
    #pragma unroll
    for (int k = 0; k < HID; ++k) acc = fmaf(xr[k], wr[k], acc);
    out[i] = acc;
}

extern "C" void kernel_launch(void* const* d_in, const int* in_sizes, int n_in,
                              void* d_out, int out_size, void* d_ws, size_t ws_size,
                              hipStream_t stream) {
    const float* x0   = (const float*)d_in[0];
    const int*   ei   = (const int*)d_in[1];
    const int E = in_sizes[1] / 2;
    const int N = in_sizes[0] / IN_CH;
    const int* srcp = ei;        // edge_index[0] = x_j (source)
    const int* dstp = ei + E;    // edge_index[1] = x_i (aggregation target)

    const float* W[4] = {(const float*)d_in[2], (const float*)d_in[5], (const float*)d_in[8],  (const float*)d_in[11]};
    const float* B[4] = {(const float*)d_in[3], (const float*)d_in[6], (const float*)d_in[9],  (const float*)d_in[12]};
    const float* A[4] = {(const float*)d_in[4], (const float*)d_in[7], (const float*)d_in[10], (const float*)d_in[13]};
    const float* fcW = (const float*)d_in[14];
    const float* fcb = (const float*)d_in[15];

    // workspace layout (floats)
    float* ws   = (float*)d_ws;
    float* hbuf = ws;                       // N*64
    float* xa   = hbuf + (size_t)N * HID;   // N*64
    float* xb   = xa   + (size_t)N * HID;   // N*64
    float* si   = xb   + (size_t)N * HID;   // N*4
    float* sj   = si   + (size_t)N * HEADS; // N*4
    float* degf = sj   + (size_t)N * HEADS; // N
    int*   degi = (int*)(degf + N);         // N

    hipMemsetAsync(degi, 0, (size_t)N * sizeof(int), stream);
    k_deg_count<<<(E + 255) / 256, 256, 0, stream>>>(dstp, degi, E);
    k_deg_to_f<<<(N + 255) / 256, 256, 0, stream>>>(degi, degf, N);

    const float* cur = x0;
    float* outbuf[2] = {xa, xb};
    for (int l = 0; l < 4; ++l) {
        int in_ch = (l == 0) ? IN_CH : HID;
        k_linear<<<N, 64, 0, stream>>>(cur, in_ch, W[l], B[l], A[l], hbuf, si, sj, N);
        float* ob = outbuf[l & 1];
        hipMemsetAsync(ob, 0, (size_t)N * HID * sizeof(float), stream);
        k_edge<<<(E + EPB - 1) / EPB, 64 * EPB, 0, stream>>>(srcp, dstp, hbuf, si, sj, degf, ob, E);
        cur = ob;
    }
    k_fc<<<(N * OUT_SIZE + 255) / 256, 256, 0, stream>>>(cur, fcW, fcb, (float*)d_out, N);
}

// Round 2
// 1636.640 us; speedup vs baseline: 1.4969x; 1.4969x over previous
//
#include <hip/hip_runtime.h>

#define NNODES 100000
#define NEDGES 1600000
#define IN_CH 128
#define HID 64
#define HEADS 4
#define OUT_CH 16
#define OUT_SIZE 4
#define NEG_SLOPE 0.2f

// ---------------- degree (int atomics, deterministic) ----------------
__global__ void k_deg_count(const int* __restrict__ dst, int* __restrict__ deg, int E) {
    int e = blockIdx.x * blockDim.x + threadIdx.x;
    if (e < E) {
        int d = dst[e];
        if ((unsigned)d < NNODES) atomicAdd(&deg[d], 1);
    }
}

__global__ void k_deg_to_f(const int* __restrict__ deg, float* __restrict__ degf, int n) {
    int i = blockIdx.x * blockDim.x + threadIdx.x;
    if (i < n) degf[i] = (float)deg[i];
}

// ---------------- tiled GEMM + fused bias + attention scores ----------------
// C[100000 x 64] = x[100000 x IN] @ W^T[IN x 64], BM=BN=64, BK=32, 256 thr, 4x4 micro-tile.
template<int IN>
__global__ __launch_bounds__(256) void k_linear_t(const float* __restrict__ x,
                         const float* __restrict__ W, const float* __restrict__ bias,
                         const float* __restrict__ att,
                         float* __restrict__ h, float* __restrict__ si, float* __restrict__ sj,
                         int n) {
    constexpr int BM = 64, BN = 64, BK = 32;
    constexpr int LDA = BM + 4;   // pad: keeps rows 16B-aligned (68*4=272B) & spreads banks
    constexpr int LDB = BN + 4;
    constexpr int LDH = BN + 4;
    __shared__ float As[BK][LDA];   // As[k][m] = x[node0+m][kk+k]
    __shared__ float Bs[BK][LDB];   // Bs[k][nc] = W[nc][kk+k]
    __shared__ float hs[BM][LDH];

    const int tid = threadIdx.x;
    const int node0 = blockIdx.x * BM;
    const int tn = (tid & 15) * 4;
    const int tm = (tid >> 4) * 4;

    float acc[4][4] = {};

    for (int kk = 0; kk < IN; kk += BK) {
        // stage x tile: 64 rows x 32 k = 2048 floats -> 2 float4 per thread
        #pragma unroll
        for (int i = 0; i < 2; ++i) {
            int idx = tid * 2 + i;          // 0..511
            int m   = idx >> 3;             // row in tile
            int c4  = (idx & 7) * 4;        // k offset
            int g = node0 + m;
            float4 v = make_float4(0.f, 0.f, 0.f, 0.f);
            if (g < n) v = *reinterpret_cast<const float4*>(&x[(size_t)g * IN + kk + c4]);
            As[c4 + 0][m] = v.x; As[c4 + 1][m] = v.y;
            As[c4 + 2][m] = v.z; As[c4 + 3][m] = v.w;
            // stage W tile (same index mapping; W is [64][IN] row-major)
            float4 w = *reinterpret_cast<const float4*>(&W[(size_t)m * IN + kk + c4]);
            Bs[c4 + 0][m] = w.x; Bs[c4 + 1][m] = w.y;
            Bs[c4 + 2][m] = w.z; Bs[c4 + 3][m] = w.w;
        }
        __syncthreads();
        #pragma unroll
        for (int k = 0; k < BK; ++k) {
            float4 a = *reinterpret_cast<const float4*>(&As[k][tm]);
            float4 b = *reinterpret_cast<const float4*>(&Bs[k][tn]);
            acc[0][0] = fmaf(a.x, b.x, acc[0][0]); acc[0][1] = fmaf(a.x, b.y, acc[0][1]);
            acc[0][2] = fmaf(a.x, b.z, acc[0][2]); acc[0][3] = fmaf(a.x, b.w, acc[0][3]);
            acc[1][0] = fmaf(a.y, b.x, acc[1][0]); acc[1][1] = fmaf(a.y, b.y, acc[1][1]);
            acc[1][2] = fmaf(a.y, b.z, acc[1][2]); acc[1][3] = fmaf(a.y, b.w, acc[1][3]);
            acc[2][0] = fmaf(a.z, b.x, acc[2][0]); acc[2][1] = fmaf(a.z, b.y, acc[2][1]);
            acc[2][2] = fmaf(a.z, b.z, acc[2][2]); acc[2][3] = fmaf(a.z, b.w, acc[2][3]);
            acc[3][0] = fmaf(a.w, b.x, acc[3][0]); acc[3][1] = fmaf(a.w, b.y, acc[3][1]);
            acc[3][2] = fmaf(a.w, b.z, acc[3][2]); acc[3][3] = fmaf(a.w, b.w, acc[3][3]);
        }
        __syncthreads();
    }

    // epilogue: + bias, write h (global + LDS for attention scores)
    float4 bv = *reinterpret_cast<const float4*>(&bias[tn]);
    #pragma unroll
    for (int i = 0; i < 4; ++i) {
        float4 v = make_float4(acc[i][0] + bv.x, acc[i][1] + bv.y,
                               acc[i][2] + bv.z, acc[i][3] + bv.w);
        *reinterpret_cast<float4*>(&hs[tm + i][tn]) = v;
        int g = node0 + tm + i;
        if (g < n) *reinterpret_cast<float4*>(&h[(size_t)g * HID + tn]) = v;
    }
    __syncthreads();

    // si/sj: 256 threads = 64 nodes x 4 heads
    int nodel = tid >> 2, head = tid & 3;
    int g = node0 + nodel;
    if (g < n) {
        const float* arow = att + head * (2 * OUT_CH);
        const float* hrow = &hs[nodel][head * OUT_CH];
        float vi = 0.f, vj = 0.f;
        #pragma unroll
        for (int c = 0; c < OUT_CH; ++c) {
            float hv = hrow[c];
            vi = fmaf(hv, arow[c], vi);
            vj = fmaf(hv, arow[OUT_CH + c], vj);
        }
        si[g * HEADS + head] = vi;
        sj[g * HEADS + head] = vj;
    }
}

// ---------------- edge scatter ----------------
// 64 threads (one channel each) per edge; 4 edges per 256-thread block.
#define EPB 4
__global__ void k_edge(const int* __restrict__ src, const int* __restrict__ dst,
                       const float* __restrict__ h, const float* __restrict__ si,
                       const float* __restrict__ sj, const float* __restrict__ degf,
                       float* __restrict__ out, int E) {
    int e = blockIdx.x * EPB + (threadIdx.x >> 6);
    if (e >= E) return;
    int t = threadIdx.x & 63;
    int s = src[e], d = dst[e];
    if ((unsigned)s >= NNODES || (unsigned)d >= NNODES) return;
    int head = t >> 4;
    float a = si[d * HEADS + head] + sj[s * HEADS + head];
    a = (a > 0.f) ? a : a * NEG_SLOPE;
    a = a / degf[d];   // true division to match reference rounding
    float v = h[(size_t)s * HID + t] * a;
    atomicAdd(&out[(size_t)d * HID + t], v);
}

// ---------------- final fc: out = x @ fcW^T + fcb ----------------
__global__ void k_fc(const float* __restrict__ x, const float* __restrict__ fcW,
                     const float* __restrict__ fcb, float* __restrict__ out, int n) {
    int i = blockIdx.x * blockDim.x + threadIdx.x;
    if (i >= n * OUT_SIZE) return;
    int node = i >> 2, o = i & 3;
    const float* xr = x + (size_t)node * HID;
    const float* wr = fcW + o * HID;
    float acc = fcb[o];
    #pragma unroll
    for (int k = 0; k < HID; ++k) acc = fmaf(xr[k], wr[k], acc);
    out[i] = acc;
}

extern "C" void kernel_launch(void* const* d_in, const int* in_sizes, int n_in,
                              void* d_out, int out_size, void* d_ws, size_t ws_size,
                              hipStream_t stream) {
    const float* x0   = (const float*)d_in[0];
    const int*   ei   = (const int*)d_in[1];
    const int E = in_sizes[1] / 2;
    const int N = in_sizes[0] / IN_CH;
    const int* srcp = ei;        // edge_index[0] = x_j (source)
    const int* dstp = ei + E;    // edge_index[1] = x_i (aggregation target)

    const float* W[4] = {(const float*)d_in[2], (const float*)d_in[5], (const float*)d_in[8],  (const float*)d_in[11]};
    const float* B[4] = {(const float*)d_in[3], (const float*)d_in[6], (const float*)d_in[9],  (const float*)d_in[12]};
    const float* A[4] = {(const float*)d_in[4], (const float*)d_in[7], (const float*)d_in[10], (const float*)d_in[13]};
    const float* fcW = (const float*)d_in[14];
    const float* fcb = (const float*)d_in[15];

    // workspace layout (floats)
    float* ws   = (float*)d_ws;
    float* hbuf = ws;                       // N*64
    float* xa   = hbuf + (size_t)N * HID;   // N*64
    float* xb   = xa   + (size_t)N * HID;   // N*64
    float* si   = xb   + (size_t)N * HID;   // N*4
    float* sj   = si   + (size_t)N * HEADS; // N*4
    float* degf = sj   + (size_t)N * HEADS; // N
    int*   degi = (int*)(degf + N);         // N

    hipMemsetAsync(degi, 0, (size_t)N * sizeof(int), stream);
    k_deg_count<<<(E + 255) / 256, 256, 0, stream>>>(dstp, degi, E);
    k_deg_to_f<<<(N + 255) / 256, 256, 0, stream>>>(degi, degf, N);

    const int nblk = (N + 63) / 64;
    const float* cur = x0;
    float* outbuf[2] = {xa, xb};
    for (int l = 0; l < 4; ++l) {
        float* ob = outbuf[l & 1];
        if (l == 0)
            k_linear_t<IN_CH><<<nblk, 256, 0, stream>>>(cur, W[l], B[l], A[l], hbuf, si, sj, N);
        else
            k_linear_t<HID><<<nblk, 256, 0, stream>>>(cur, W[l], B[l], A[l], hbuf, si, sj, N);
        hipMemsetAsync(ob, 0, (size_t)N * HID * sizeof(float), stream);
        k_edge<<<(E + EPB - 1) / EPB, 64 * EPB, 0, stream>>>(srcp, dstp, hbuf, si, sj, degf, ob, E);
        cur = ob;
    }
    k_fc<<<(N * OUT_SIZE + 255) / 256, 256, 0, stream>>>(cur, fcW, fcb, (float*)d_out, N);
}

// Round 3
// 748.257 us; speedup vs baseline: 3.2741x; 2.1873x over previous
//
#include <hip/hip_runtime.h>

#define NNODES 100000
#define NEDGES 1600000
#define IN_CH 128
#define HID 64
#define HEADS 4
#define OUT_CH 16
#define OUT_SIZE 4
#define NEG_SLOPE 0.2f

// ---------------- degree (int atomics, deterministic) ----------------
__global__ void k_deg_count(const int* __restrict__ dst, int* __restrict__ deg, int E) {
    int e = blockIdx.x * blockDim.x + threadIdx.x;
    if (e < E) {
        int d = dst[e];
        if ((unsigned)d < NNODES) atomicAdd(&deg[d], 1);
    }
}

__global__ void k_deg_to_f(const int* __restrict__ deg, float* __restrict__ degf, int n) {
    int i = blockIdx.x * blockDim.x + threadIdx.x;
    if (i < n) degf[i] = (float)deg[i];
}

// ---------------- exclusive scan (3-pass) for CSR rowptr ----------------
__global__ void k_scan1(const int* __restrict__ deg, int* __restrict__ incl,
                        int* __restrict__ bsum, int n) {
    int i = blockIdx.x * 256 + threadIdx.x;
    int lane = threadIdx.x & 63;
    int w = threadIdx.x >> 6;
    int val = (i < n) ? deg[i] : 0;
    #pragma unroll
    for (int off = 1; off < 64; off <<= 1) {
        int o = __shfl_up(val, off, 64);
        if (lane >= off) val += o;
    }
    __shared__ int wsum[4];
    if (lane == 63) wsum[w] = val;
    __syncthreads();
    for (int k = 0; k < w; ++k) val += wsum[k];
    if (i < n) incl[i] = val;
    if (threadIdx.x == 255) bsum[blockIdx.x] = val;
}

__global__ void k_scan2(int* __restrict__ bsum, int nb) {
    if (blockIdx.x == 0 && threadIdx.x == 0) {
        int run = 0;
        for (int b = 0; b < nb; ++b) { int t = bsum[b]; bsum[b] = run; run += t; }
    }
}

__global__ void k_scan3(const int* __restrict__ incl, const int* __restrict__ deg,
                        const int* __restrict__ bsum, int* __restrict__ rowptr, int n, int E) {
    int i = blockIdx.x * 256 + threadIdx.x;
    if (i < n) rowptr[i] = incl[i] - deg[i] + bsum[i >> 8];
    if (i == 0) rowptr[n] = E;
}

__global__ void k_csr_fill(const int* __restrict__ src, const int* __restrict__ dst,
                           const int* __restrict__ rowptr, int* __restrict__ cursor,
                           int* __restrict__ csr_src, int E) {
    int e = blockIdx.x * 256 + threadIdx.x;
    if (e < E) {
        int d = dst[e];
        int pos = atomicAdd(&cursor[d], 1);
        csr_src[rowptr[d] + pos] = src[e];
    }
}

// ---------------- tiled GEMM + fused bias + attention scores ----------------
template<int IN>
__global__ __launch_bounds__(256) void k_linear_t(const float* __restrict__ x,
                         const float* __restrict__ W, const float* __restrict__ bias,
                         const float* __restrict__ att,
                         float* __restrict__ h, float* __restrict__ si, float* __restrict__ sj,
                         int n) {
    constexpr int BM = 64, BN = 64, BK = 32;
    constexpr int LDA = BM + 4;
    constexpr int LDB = BN + 4;
    constexpr int LDH = BN + 4;
    __shared__ float As[BK][LDA];
    __shared__ float Bs[BK][LDB];
    __shared__ float hs[BM][LDH];

    const int tid = threadIdx.x;
    const int node0 = blockIdx.x * BM;
    const int tn = (tid & 15) * 4;
    const int tm = (tid >> 4) * 4;

    float acc[4][4] = {};

    for (int kk = 0; kk < IN; kk += BK) {
        #pragma unroll
        for (int i = 0; i < 2; ++i) {
            int idx = tid * 2 + i;
            int m   = idx >> 3;
            int c4  = (idx & 7) * 4;
            int g = node0 + m;
            float4 v = make_float4(0.f, 0.f, 0.f, 0.f);
            if (g < n) v = *reinterpret_cast<const float4*>(&x[(size_t)g * IN + kk + c4]);
            As[c4 + 0][m] = v.x; As[c4 + 1][m] = v.y;
            As[c4 + 2][m] = v.z; As[c4 + 3][m] = v.w;
            float4 w = *reinterpret_cast<const float4*>(&W[(size_t)m * IN + kk + c4]);
            Bs[c4 + 0][m] = w.x; Bs[c4 + 1][m] = w.y;
            Bs[c4 + 2][m] = w.z; Bs[c4 + 3][m] = w.w;
        }
        __syncthreads();
        #pragma unroll
        for (int k = 0; k < BK; ++k) {
            float4 a = *reinterpret_cast<const float4*>(&As[k][tm]);
            float4 b = *reinterpret_cast<const float4*>(&Bs[k][tn]);
            acc[0][0] = fmaf(a.x, b.x, acc[0][0]); acc[0][1] = fmaf(a.x, b.y, acc[0][1]);
            acc[0][2] = fmaf(a.x, b.z, acc[0][2]); acc[0][3] = fmaf(a.x, b.w, acc[0][3]);
            acc[1][0] = fmaf(a.y, b.x, acc[1][0]); acc[1][1] = fmaf(a.y, b.y, acc[1][1]);
            acc[1][2] = fmaf(a.y, b.z, acc[1][2]); acc[1][3] = fmaf(a.y, b.w, acc[1][3]);
            acc[2][0] = fmaf(a.z, b.x, acc[2][0]); acc[2][1] = fmaf(a.z, b.y, acc[2][1]);
            acc[2][2] = fmaf(a.z, b.z, acc[2][2]); acc[2][3] = fmaf(a.z, b.w, acc[2][3]);
            acc[3][0] = fmaf(a.w, b.x, acc[3][0]); acc[3][1] = fmaf(a.w, b.y, acc[3][1]);
            acc[3][2] = fmaf(a.w, b.z, acc[3][2]); acc[3][3] = fmaf(a.w, b.w, acc[3][3]);
        }
        __syncthreads();
    }

    float4 bv = *reinterpret_cast<const float4*>(&bias[tn]);
    #pragma unroll
    for (int i = 0; i < 4; ++i) {
        float4 v = make_float4(acc[i][0] + bv.x, acc[i][1] + bv.y,
                               acc[i][2] + bv.z, acc[i][3] + bv.w);
        *reinterpret_cast<float4*>(&hs[tm + i][tn]) = v;
        int g = node0 + tm + i;
        if (g < n) *reinterpret_cast<float4*>(&h[(size_t)g * HID + tn]) = v;
    }
    __syncthreads();

    int nodel = tid >> 2, head = tid & 3;
    int g = node0 + nodel;
    if (g < n) {
        const float* arow = att + head * (2 * OUT_CH);
        const float* hrow = &hs[nodel][head * OUT_CH];
        float vi = 0.f, vj = 0.f;
        #pragma unroll
        for (int c = 0; c < OUT_CH; ++c) {
            float hv = hrow[c];
            vi = fmaf(hv, arow[c], vi);
            vj = fmaf(hv, arow[OUT_CH + c], vj);
        }
        si[g * HEADS + head] = vi;
        sj[g * HEADS + head] = vj;
    }
}

// ---------------- CSR gather aggregation (no atomics) ----------------
// One 64-lane wave per dst node; lane = output channel. 4 nodes / 256-thr block.
__global__ __launch_bounds__(256) void k_gather(const int* __restrict__ csr_src,
                        const int* __restrict__ rowptr,
                        const float* __restrict__ h, const float* __restrict__ si,
                        const float* __restrict__ sj, const float* __restrict__ degf,
                        float* __restrict__ out, int n) {
    int node = blockIdx.x * 4 + (threadIdx.x >> 6);
    if (node >= n) return;
    int t = threadIdx.x & 63;
    int head = t >> 4;
    int beg = rowptr[node], end = rowptr[node + 1];
    float sid = si[node * HEADS + head];
    float invd = 1.0f / degf[node];   // unused (inf) if row empty
    float acc = 0.f;
    int j = beg;
    for (; j + 2 <= end; j += 2) {
        int s0 = csr_src[j], s1 = csr_src[j + 1];
        float a0 = sid + sj[s0 * HEADS + head];
        float a1 = sid + sj[s1 * HEADS + head];
        a0 = ((a0 > 0.f) ? a0 : a0 * NEG_SLOPE) * invd;
        a1 = ((a1 > 0.f) ? a1 : a1 * NEG_SLOPE) * invd;
        float h0 = h[(size_t)s0 * HID + t];
        float h1 = h[(size_t)s1 * HID + t];
        acc = fmaf(h0, a0, acc);
        acc = fmaf(h1, a1, acc);
    }
    if (j < end) {
        int s0 = csr_src[j];
        float a0 = sid + sj[s0 * HEADS + head];
        a0 = ((a0 > 0.f) ? a0 : a0 * NEG_SLOPE) * invd;
        acc = fmaf(h[(size_t)s0 * HID + t], a0, acc);
    }
    out[(size_t)node * HID + t] = acc;
}

// ---------------- final fc ----------------
__global__ void k_fc(const float* __restrict__ x, const float* __restrict__ fcW,
                     const float* __restrict__ fcb, float* __restrict__ out, int n) {
    int i = blockIdx.x * blockDim.x + threadIdx.x;
    if (i >= n * OUT_SIZE) return;
    int node = i >> 2, o = i & 3;
    const float* xr = x + (size_t)node * HID;
    const float* wr = fcW + o * HID;
    float acc = fcb[o];
    #pragma unroll
    for (int k = 0; k < HID; ++k) acc = fmaf(xr[k], wr[k], acc);
    out[i] = acc;
}

extern "C" void kernel_launch(void* const* d_in, const int* in_sizes, int n_in,
                              void* d_out, int out_size, void* d_ws, size_t ws_size,
                              hipStream_t stream) {
    const float* x0   = (const float*)d_in[0];
    const int*   ei   = (const int*)d_in[1];
    const int E = in_sizes[1] / 2;
    const int N = in_sizes[0] / IN_CH;
    const int* srcp = ei;        // edge_index[0] = x_j (source)
    const int* dstp = ei + E;    // edge_index[1] = x_i (aggregation target)

    const float* W[4] = {(const float*)d_in[2], (const float*)d_in[5], (const float*)d_in[8],  (const float*)d_in[11]};
    const float* B[4] = {(const float*)d_in[3], (const float*)d_in[6], (const float*)d_in[9],  (const float*)d_in[12]};
    const float* A[4] = {(const float*)d_in[4], (const float*)d_in[7], (const float*)d_in[10], (const float*)d_in[13]};
    const float* fcW = (const float*)d_in[14];
    const float* fcb = (const float*)d_in[15];

    // workspace layout
    float* ws    = (float*)d_ws;
    float* hbuf  = ws;                        // N*64
    float* xa    = hbuf + (size_t)N * HID;    // N*64
    float* si    = xa   + (size_t)N * HID;    // N*4
    float* sj    = si   + (size_t)N * HEADS;  // N*4
    float* degf  = sj   + (size_t)N * HEADS;  // N
    int*   degi  = (int*)(degf + N);          // N
    int*   rowptr= degi + N;                  // N+1
    int*   incl  = rowptr + N + 1;            // N
    int*   bsum  = incl + N;                  // 1024
    int*   cursor= bsum + 1024;               // N
    int*   csr   = cursor + N;                // E

    const int nb = (N + 255) / 256;
    hipMemsetAsync(degi, 0, (size_t)N * sizeof(int), stream);
    hipMemsetAsync(cursor, 0, (size_t)N * sizeof(int), stream);
    k_deg_count<<<(E + 255) / 256, 256, 0, stream>>>(dstp, degi, E);
    k_deg_to_f<<<nb, 256, 0, stream>>>(degi, degf, N);
    k_scan1<<<nb, 256, 0, stream>>>(degi, incl, bsum, N);
    k_scan2<<<1, 64, 0, stream>>>(bsum, nb);
    k_scan3<<<nb, 256, 0, stream>>>(incl, degi, bsum, rowptr, N, E);
    k_csr_fill<<<(E + 255) / 256, 256, 0, stream>>>(srcp, dstp, rowptr, cursor, csr, E);

    const int nblk = (N + 63) / 64;
    const int gblk = (N + 3) / 4;
    const float* cur = x0;
    for (int l = 0; l < 4; ++l) {
        if (l == 0)
            k_linear_t<IN_CH><<<nblk, 256, 0, stream>>>(cur, W[l], B[l], A[l], hbuf, si, sj, N);
        else
            k_linear_t<HID><<<nblk, 256, 0, stream>>>(cur, W[l], B[l], A[l], hbuf, si, sj, N);
        float* ob = (l == 0) ? xa : (float*)cur;   // in-place from layer 1 on
        k_gather<<<gblk, 256, 0, stream>>>(csr, rowptr, hbuf, si, sj, degf, ob, N);
        cur = ob;
    }
    k_fc<<<(N * OUT_SIZE + 255) / 256, 256, 0, stream>>>(cur, fcW, fcb, (float*)d_out, N);
}

// Round 4
// 639.878 us; speedup vs baseline: 3.8286x; 1.1694x over previous
//
#include <hip/hip_runtime.h>

#define NNODES 100000
#define NEDGES 1600000
#define IN_CH 128
#define HID 64
#define HEADS 4
#define OUT_CH 16
#define OUT_SIZE 4
#define NEG_SLOPE 0.2f

// ---------------- degree (int atomics, deterministic) ----------------
__global__ void k_deg_count(const int* __restrict__ dst, int* __restrict__ deg, int E) {
    int e = blockIdx.x * blockDim.x + threadIdx.x;
    if (e < E) {
        int d = dst[e];
        if ((unsigned)d < NNODES) atomicAdd(&deg[d], 1);
    }
}

__global__ void k_deg_to_f(const int* __restrict__ deg, float* __restrict__ degf, int n) {
    int i = blockIdx.x * blockDim.x + threadIdx.x;
    if (i < n) degf[i] = (float)deg[i];
}

// ---------------- exclusive scan (3-pass) for CSR rowptr ----------------
__global__ void k_scan1(const int* __restrict__ deg, int* __restrict__ incl,
                        int* __restrict__ bsum, int n) {
    int i = blockIdx.x * 256 + threadIdx.x;
    int lane = threadIdx.x & 63;
    int w = threadIdx.x >> 6;
    int val = (i < n) ? deg[i] : 0;
    #pragma unroll
    for (int off = 1; off < 64; off <<= 1) {
        int o = __shfl_up(val, off, 64);
        if (lane >= off) val += o;
    }
    __shared__ int wsum[4];
    if (lane == 63) wsum[w] = val;
    __syncthreads();
    for (int k = 0; k < w; ++k) val += wsum[k];
    if (i < n) incl[i] = val;
    if (threadIdx.x == 255) bsum[blockIdx.x] = val;
}

__global__ void k_scan2(int* __restrict__ bsum, int nb) {
    if (blockIdx.x == 0 && threadIdx.x == 0) {
        int run = 0;
        for (int b = 0; b < nb; ++b) { int t = bsum[b]; bsum[b] = run; run += t; }
    }
}

__global__ void k_scan3(const int* __restrict__ incl, const int* __restrict__ deg,
                        const int* __restrict__ bsum, int* __restrict__ rowptr, int n, int E) {
    int i = blockIdx.x * 256 + threadIdx.x;
    if (i < n) rowptr[i] = incl[i] - deg[i] + bsum[i >> 8];
    if (i == 0) rowptr[n] = E;
}

__global__ void k_csr_fill(const int* __restrict__ src, const int* __restrict__ dst,
                           const int* __restrict__ rowptr, int* __restrict__ cursor,
                           int* __restrict__ csr_src, int E) {
    int e = blockIdx.x * 256 + threadIdx.x;
    if (e < E) {
        int d = dst[e];
        int pos = atomicAdd(&cursor[d], 1);
        csr_src[rowptr[d] + pos] = src[e];
    }
}

// ---------------- tiled GEMM + fused bias + attention scores ----------------
template<int IN>
__global__ __launch_bounds__(256) void k_linear_t(const float* __restrict__ x,
                         const float* __restrict__ W, const float* __restrict__ bias,
                         const float* __restrict__ att,
                         float* __restrict__ h, float* __restrict__ si, float* __restrict__ sj,
                         int n) {
    constexpr int BM = 64, BN = 64, BK = 32;
    constexpr int LDA = BM + 4;
    constexpr int LDB = BN + 4;
    constexpr int LDH = BN + 4;
    __shared__ float As[BK][LDA];
    __shared__ float Bs[BK][LDB];
    __shared__ float hs[BM][LDH];

    const int tid = threadIdx.x;
    const int node0 = blockIdx.x * BM;
    const int tn = (tid & 15) * 4;
    const int tm = (tid >> 4) * 4;

    float acc[4][4] = {};

    for (int kk = 0; kk < IN; kk += BK) {
        #pragma unroll
        for (int i = 0; i < 2; ++i) {
            int idx = tid * 2 + i;
            int m   = idx >> 3;
            int c4  = (idx & 7) * 4;
            int g = node0 + m;
            float4 v = make_float4(0.f, 0.f, 0.f, 0.f);
            if (g < n) v = *reinterpret_cast<const float4*>(&x[(size_t)g * IN + kk + c4]);
            As[c4 + 0][m] = v.x; As[c4 + 1][m] = v.y;
            As[c4 + 2][m] = v.z; As[c4 + 3][m] = v.w;
            float4 w = *reinterpret_cast<const float4*>(&W[(size_t)m * IN + kk + c4]);
            Bs[c4 + 0][m] = w.x; Bs[c4 + 1][m] = w.y;
            Bs[c4 + 2][m] = w.z; Bs[c4 + 3][m] = w.w;
        }
        __syncthreads();
        #pragma unroll
        for (int k = 0; k < BK; ++k) {
            float4 a = *reinterpret_cast<const float4*>(&As[k][tm]);
            float4 b = *reinterpret_cast<const float4*>(&Bs[k][tn]);
            acc[0][0] = fmaf(a.x, b.x, acc[0][0]); acc[0][1] = fmaf(a.x, b.y, acc[0][1]);
            acc[0][2] = fmaf(a.x, b.z, acc[0][2]); acc[0][3] = fmaf(a.x, b.w, acc[0][3]);
            acc[1][0] = fmaf(a.y, b.x, acc[1][0]); acc[1][1] = fmaf(a.y, b.y, acc[1][1]);
            acc[1][2] = fmaf(a.y, b.z, acc[1][2]); acc[1][3] = fmaf(a.y, b.w, acc[1][3]);
            acc[2][0] = fmaf(a.z, b.x, acc[2][0]); acc[2][1] = fmaf(a.z, b.y, acc[2][1]);
            acc[2][2] = fmaf(a.z, b.z, acc[2][2]); acc[2][3] = fmaf(a.z, b.w, acc[2][3]);
            acc[3][0] = fmaf(a.w, b.x, acc[3][0]); acc[3][1] = fmaf(a.w, b.y, acc[3][1]);
            acc[3][2] = fmaf(a.w, b.z, acc[3][2]); acc[3][3] = fmaf(a.w, b.w, acc[3][3]);
        }
        __syncthreads();
    }

    float4 bv = *reinterpret_cast<const float4*>(&bias[tn]);
    #pragma unroll
    for (int i = 0; i < 4; ++i) {
        float4 v = make_float4(acc[i][0] + bv.x, acc[i][1] + bv.y,
                               acc[i][2] + bv.z, acc[i][3] + bv.w);
        *reinterpret_cast<float4*>(&hs[tm + i][tn]) = v;
        int g = node0 + tm + i;
        if (g < n) *reinterpret_cast<float4*>(&h[(size_t)g * HID + tn]) = v;
    }
    __syncthreads();

    int nodel = tid >> 2, head = tid & 3;
    int g = node0 + nodel;
    if (g < n) {
        const float* arow = att + head * (2 * OUT_CH);
        const float* hrow = &hs[nodel][head * OUT_CH];
        float vi = 0.f, vj = 0.f;
        #pragma unroll
        for (int c = 0; c < OUT_CH; ++c) {
            float hv = hrow[c];
            vi = fmaf(hv, arow[c], vi);
            vj = fmaf(hv, arow[OUT_CH + c], vj);
        }
        si[g * HEADS + head] = vi;
        sj[g * HEADS + head] = vj;
    }
}

// ---------------- CSR gather aggregation (no atomics) ----------------
// 4 nodes per wave (16 lanes each, float4 per lane) -> 4 independent gather
// streams per wave; unroll 2 -> 8 loads in flight. 16 nodes / 256-thr block.
__global__ __launch_bounds__(256) void k_gather(const int* __restrict__ csr_src,
                        const int* __restrict__ rowptr,
                        const float* __restrict__ h, const float* __restrict__ si,
                        const float* __restrict__ sj, const float* __restrict__ degf,
                        float* __restrict__ out, int n) {
    const int wid  = threadIdx.x >> 6;
    const int lane = threadIdx.x & 63;
    const int l16  = lane & 15;         // position within node group
    const int head = l16 >> 2;
    const int node = blockIdx.x * 16 + wid * 4 + (lane >> 4);
    const bool active = node < n;

    int beg = 0, end = 0;
    float sid = 0.f, invd = 0.f;
    if (active) {
        beg = rowptr[node];
        end = rowptr[node + 1];
        sid = si[node * HEADS + head];
        if (end > beg) invd = 1.0f / degf[node];
    }

    float4 acc = make_float4(0.f, 0.f, 0.f, 0.f);
    int j = beg;
    while (__any(j < end)) {
        bool p0 = j < end;
        bool p1 = j + 1 < end;
        int j0 = p0 ? j : 0;
        int j1 = p1 ? j + 1 : 0;
        int s0 = csr_src[j0];
        int s1 = csr_src[j1];
        float e0 = sj[s0 * HEADS + head];
        float e1 = sj[s1 * HEADS + head];
        float4 h0 = *reinterpret_cast<const float4*>(&h[(size_t)s0 * HID + (l16 << 2)]);
        float4 h1 = *reinterpret_cast<const float4*>(&h[(size_t)s1 * HID + (l16 << 2)]);
        float a0 = sid + e0; a0 = (a0 > 0.f) ? a0 : a0 * NEG_SLOPE; a0 = p0 ? a0 : 0.f;
        float a1 = sid + e1; a1 = (a1 > 0.f) ? a1 : a1 * NEG_SLOPE; a1 = p1 ? a1 : 0.f;
        acc.x = fmaf(h0.x, a0, acc.x); acc.y = fmaf(h0.y, a0, acc.y);
        acc.z = fmaf(h0.z, a0, acc.z); acc.w = fmaf(h0.w, a0, acc.w);
        acc.x = fmaf(h1.x, a1, acc.x); acc.y = fmaf(h1.y, a1, acc.y);
        acc.z = fmaf(h1.z, a1, acc.z); acc.w = fmaf(h1.w, a1, acc.w);
        j += 2;
    }
    if (active) {
        acc.x *= invd; acc.y *= invd; acc.z *= invd; acc.w *= invd;
        *reinterpret_cast<float4*>(&out[(size_t)node * HID + (l16 << 2)]) = acc;
    }
}

// ---------------- final fc ----------------
__global__ void k_fc(const float* __restrict__ x, const float* __restrict__ fcW,
                     const float* __restrict__ fcb, float* __restrict__ out, int n) {
    int i = blockIdx.x * blockDim.x + threadIdx.x;
    if (i >= n * OUT_SIZE) return;
    int node = i >> 2, o = i & 3;
    const float* xr = x + (size_t)node * HID;
    const float* wr = fcW + o * HID;
    float acc = fcb[o];
    #pragma unroll
    for (int k = 0; k < HID; ++k) acc = fmaf(xr[k], wr[k], acc);
    out[i] = acc;
}

extern "C" void kernel_launch(void* const* d_in, const int* in_sizes, int n_in,
                              void* d_out, int out_size, void* d_ws, size_t ws_size,
                              hipStream_t stream) {
    const float* x0   = (const float*)d_in[0];
    const int*   ei   = (const int*)d_in[1];
    const int E = in_sizes[1] / 2;
    const int N = in_sizes[0] / IN_CH;
    const int* srcp = ei;        // edge_index[0] = x_j (source)
    const int* dstp = ei + E;    // edge_index[1] = x_i (aggregation target)

    const float* W[4] = {(const float*)d_in[2], (const float*)d_in[5], (const float*)d_in[8],  (const float*)d_in[11]};
    const float* B[4] = {(const float*)d_in[3], (const float*)d_in[6], (const float*)d_in[9],  (const float*)d_in[12]};
    const float* A[4] = {(const float*)d_in[4], (const float*)d_in[7], (const float*)d_in[10], (const float*)d_in[13]};
    const float* fcW = (const float*)d_in[14];
    const float* fcb = (const float*)d_in[15];

    // workspace layout
    float* ws    = (float*)d_ws;
    float* hbuf  = ws;                        // N*64
    float* xa    = hbuf + (size_t)N * HID;    // N*64
    float* si    = xa   + (size_t)N * HID;    // N*4
    float* sj    = si   + (size_t)N * HEADS;  // N*4
    float* degf  = sj   + (size_t)N * HEADS;  // N
    int*   degi  = (int*)(degf + N);          // N
    int*   rowptr= degi + N;                  // N+1
    int*   incl  = rowptr + N + 1;            // N
    int*   bsum  = incl + N;                  // 1024
    int*   cursor= bsum + 1024;               // N
    int*   csr   = cursor + N;                // E

    const int nb = (N + 255) / 256;
    hipMemsetAsync(degi, 0, (size_t)N * sizeof(int), stream);
    hipMemsetAsync(cursor, 0, (size_t)N * sizeof(int), stream);
    k_deg_count<<<(E + 255) / 256, 256, 0, stream>>>(dstp, degi, E);
    k_deg_to_f<<<nb, 256, 0, stream>>>(degi, degf, N);
    k_scan1<<<nb, 256, 0, stream>>>(degi, incl, bsum, N);
    k_scan2<<<1, 64, 0, stream>>>(bsum, nb);
    k_scan3<<<nb, 256, 0, stream>>>(incl, degi, bsum, rowptr, N, E);
    k_csr_fill<<<(E + 255) / 256, 256, 0, stream>>>(srcp, dstp, rowptr, cursor, csr, E);

    const int nblk = (N + 63) / 64;
    const int gblk = (N + 15) / 16;
    const float* cur = x0;
    for (int l = 0; l < 4; ++l) {
        if (l == 0)
            k_linear_t<IN_CH><<<nblk, 256, 0, stream>>>(cur, W[l], B[l], A[l], hbuf, si, sj, N);
        else
            k_linear_t<HID><<<nblk, 256, 0, stream>>>(cur, W[l], B[l], A[l], hbuf, si, sj, N);
        float* ob = (l == 0) ? xa : (float*)cur;   // in-place from layer 1 on
        k_gather<<<gblk, 256, 0, stream>>>(csr, rowptr, hbuf, si, sj, degf, ob, N);
        cur = ob;
    }
    k_fc<<<(N * OUT_SIZE + 255) / 256, 256, 0, stream>>>(cur, fcW, fcb, (float*)d_out, N);
}